// Round 6
// baseline (452.079 us; speedup 1.0000x reference)
//
#include <hip/hip_runtime.h>

constexpr int NH = 16;
constexpr int SEQ = 2048;
constexpr int DMODEL = 2048;
constexpr int HDIM = 128;
constexpr int NB = 2;
constexpr int MTOT = NB * SEQ;                 // 4096
constexpr long NEL = (long)NB * SEQ * DMODEL;  // 8388608 activation elements
constexpr long WEL = (long)DMODEL * DMODEL;    // 4194304 weight elements
// fused-QKV workspace requirement (bytes): 4 activations + 3 weights + bias cat
constexpr size_t FUSED_WS = 2ul * (4 * NEL + 3 * WEL + 12288);

typedef __attribute__((ext_vector_type(8))) __bf16 bf16x8;
typedef __attribute__((ext_vector_type(4))) float f32x4;

__device__ __forceinline__ float bf2f(ushort u) {
  union { uint i; float f; } v; v.i = ((uint)u) << 16; return v.f;
}
__device__ __forceinline__ ushort f2bf(float f) {
  union { float f; uint i; } v; v.f = f;
  uint r = (v.i + 0x7FFFu + ((v.i >> 16) & 1u)) >> 16;
  return (ushort)r;
}
// round-half-up bf16: 2 VALU ops; P>0 so tie bias is negligible (hot path only)
__device__ __forceinline__ ushort f2bf_rhu(float f) {
  union { float f; uint i; } v; v.f = f;
  return (ushort)((v.i + 0x8000u) >> 16);
}
__device__ __forceinline__ float fast_exp2(float x) {
#if __has_builtin(__builtin_amdgcn_exp2f)
  return __builtin_amdgcn_exp2f(x);
#else
  float r;
  asm volatile("v_exp_f32 %0, %1\n\ts_nop 0" : "=v"(r) : "v"(x));
  return r;
#endif
}

// ---------------------------------------------------------------------------
// fp32 -> bf16 conversion (inputs are float32 per the reference contract).
// ---------------------------------------------------------------------------
__global__ __launch_bounds__(256) void conv_f32_bf16(
    const float* __restrict__ s, ushort* __restrict__ d, int n4) {
  const int i = blockIdx.x * 256 + threadIdx.x;
  if (i < n4) {
    const float4 v = ((const float4*)s)[i];
    ushort4 o;
    o.x = f2bf(v.x); o.y = f2bf(v.y); o.z = f2bf(v.z); o.w = f2bf(v.w);
    ((ushort4*)d)[i] = o;
  }
}

// concat 3 x 2048 fp32 biases for the fused QKV GEMM
__global__ __launch_bounds__(256) void bias_cat(
    const float* __restrict__ a, const float* __restrict__ b,
    const float* __restrict__ c, float* __restrict__ o) {
  const int i = blockIdx.x * 256 + threadIdx.x;  // grid 24 -> 6144
  o[i] = (i < 2048) ? a[i] : (i < 4096) ? b[i - 2048] : c[i - 4096];
}

// ---------------------------------------------------------------------------
// Shared GEMM plumbing: global_load_lds + XOR swizzle (T2) both-sides.
// ---------------------------------------------------------------------------
#define GLDS(src, dst)                                              \
  __builtin_amdgcn_global_load_lds(                                 \
      (const __attribute__((address_space(1))) void*)(src),         \
      (__attribute__((address_space(3))) void*)(dst), 16, 0, 0)

#define BARX() __builtin_amdgcn_s_barrier()
#define WAITV(n) asm volatile("s_waitcnt vmcnt(" #n ")" ::: "memory")
#define WAITL() asm volatile("s_waitcnt lgkmcnt(0)" ::: "memory")

// ---------------------------------------------------------------------------
// gemm384: 128x384-tile, 3-phase/K-tile bt-GEMM (m201-heft phases at 100%
// duty). C[M,N] = A[M,K]@B[N,K]^T + bias. 8 waves (2M x 4N), per-wave 64x96,
// BK=64, LDS 128 KiB (A 2x16KB, B 2x48KB in three 128-row thirds).
// Grid (fused QKV): 32x16 = 512 = 2 exact rounds on 256 CUs.
// Counted vmcnt(10) at ph0/ph2 only; T2 swizzle; T5 setprio.
// ---------------------------------------------------------------------------
#define G3_STG_A(d, kt) do {                                        \
    const ushort* _s = gA + (long)(kt) * 64;                        \
    ushort* _d = smem + (d) * 8192 + w * 512;                       \
    GLDS(_s, _d);                                                   \
    GLDS(_s + 64 * (long)K, _d + 4096);                             \
  } while (0)

#define G3_STG_B(d, j, kt) do {                                     \
    const ushort* _s = gB + (long)(j) * 128 * K + (long)(kt) * 64;  \
    ushort* _d = smem + 16384 + (d) * 24576 + (j) * 8192 + w * 512; \
    GLDS(_s, _d);                                                   \
    GLDS(_s + 64 * (long)K, _d + 4096);                             \
  } while (0)

#define G3_LDA(d) do {                                              \
    const ushort* _p = smem + (d) * 8192 + (wm * 64 + l16) * 64;    \
    _Pragma("unroll")                                               \
    for (int _i = 0; _i < 4; _i++) {                                \
      afr[_i][0] = *(const bf16x8*)(_p + _i * 1024 + sw0);          \
      afr[_i][1] = *(const bf16x8*)(_p + _i * 1024 + sw1);          \
    }                                                               \
  } while (0)

#define G3_LDB(d, j, s) do {                                        \
    const ushort* _p = smem + 16384 + (d) * 24576 + (j) * 8192 +    \
                       (wn * 32 + l16) * 64;                        \
    _Pragma("unroll")                                               \
    for (int _j = 0; _j < 2; _j++) {                                \
      bfr[s][_j][0] = *(const bf16x8*)(_p + _j * 1024 + sw0);       \
      bfr[s][_j][1] = *(const bf16x8*)(_p + _j * 1024 + sw1);       \
    }                                                               \
  } while (0)

#define G3_MMA(s, j) do {                                           \
    __builtin_amdgcn_s_setprio(1);                                  \
    _Pragma("unroll")                                               \
    for (int _i = 0; _i < 4; _i++)                                  \
      _Pragma("unroll")                                             \
      for (int _j = 0; _j < 2; _j++) {                              \
        acc[_i][(j) * 2 + _j] = __builtin_amdgcn_mfma_f32_16x16x32_bf16( \
            afr[_i][0], bfr[s][_j][0], acc[_i][(j) * 2 + _j], 0, 0, 0);  \
        acc[_i][(j) * 2 + _j] = __builtin_amdgcn_mfma_f32_16x16x32_bf16( \
            afr[_i][1], bfr[s][_j][1], acc[_i][(j) * 2 + _j], 0, 0, 0);  \
      }                                                             \
    __builtin_amdgcn_s_setprio(0);                                  \
  } while (0)

template <int MODE>
__global__ __launch_bounds__(512, 2) void gemm384(
    const ushort* __restrict__ A, const ushort* __restrict__ Bw,
    const float* __restrict__ bias, void* __restrict__ Cv,
    int M, int N, int K) {
  __shared__ __align__(16) ushort smem[65536];
  const int tid = threadIdx.x;
  const int w = tid >> 6, lane = tid & 63;
  const int quad = lane >> 4, l16 = lane & 15;
  const int wm = w >> 2, wn = w & 3;  // 2M x 4N waves, per-wave 64x96
  const int nbm = M >> 7, nbn = N / 384;
  const int rm = nbm >> 1, rn = nbn >> 2;
  const int xcd = blockIdx.x & 7, loc = blockIdx.x >> 3;
  const int bm = (xcd >> 2) * rm + (loc % rm);
  const int bn = (xcd & 3) * rn + (loc / rm);
  const int m0 = bm << 7, n0 = bn * 384;
  const int KT = K >> 6;  // K=2048 -> 32 (even)

  const int srow = tid >> 3;
  const int scol = (((tid & 7) ^ ((tid >> 3) & 7)) << 3);
  const ushort* gA = A + (long)(m0 + srow) * K + scol;
  const ushort* gB = Bw + (long)(n0 + srow) * K + scol;
  const int sw0 = ((quad ^ (l16 & 7)) << 3);
  const int sw1 = (((4 + quad) ^ (l16 & 7)) << 3);

  f32x4 acc[4][6] = {};   // [m-frag][third*2 + j]
  bf16x8 afr[4][2];       // A frags [m-frag][kk]
  bf16x8 bfr[2][2][2];    // B frag sets [set][j][kk]

  G3_STG_A(0, 0);
  G3_STG_B(0, 0, 0); G3_STG_B(0, 1, 0); G3_STG_B(0, 2, 0);
  G3_STG_A(1, 1);
  G3_STG_B(1, 0, 1); G3_STG_B(1, 1, 1);
  WAITV(10);
  BARX();
  G3_LDA(0); G3_LDB(0, 0, 0);
  WAITL();
  BARX();

  for (int t = 0; t < KT; t += 2) {
    const int e2 = (t + 2 < KT) ? t + 2 : 0;   // phantom -> L2-hot
    const int e3 = (t + 3 < KT) ? t + 3 : 1;
    // ================= tile t (buf 0) =================
    G3_STG_B(1, 2, t + 1);
    G3_STG_A(0, e2);
    WAITV(10); BARX(); WAITL();
    G3_MMA(0, 0);
    G3_LDB(0, 1, 1);          // B1(t) -> set1
    BARX();
    G3_STG_B(0, 0, e2);
    BARX(); WAITL();
    G3_MMA(1, 1);
    G3_LDB(0, 2, 0);          // B2(t) -> set0
    BARX();
    G3_STG_B(0, 1, e2);
    WAITV(10); BARX(); WAITL();
    G3_MMA(0, 2);
    G3_LDA(1);                // A(t+1)
    G3_LDB(1, 0, 1);          // B0(t+1) -> set1
    BARX();
    // ================= tile t+1 (buf 1) =================
    G3_STG_B(0, 2, e2);
    G3_STG_A(1, e3);
    WAITV(10); BARX(); WAITL();
    G3_MMA(1, 0);
    G3_LDB(1, 1, 0);          // B1(t+1) -> set0
    BARX();
    G3_STG_B(1, 0, e3);
    BARX(); WAITL();
    G3_MMA(0, 1);
    G3_LDB(1, 2, 1);          // B2(t+1) -> set1
    BARX();
    G3_STG_B(1, 1, e3);
    WAITV(10); BARX(); WAITL();
    G3_MMA(1, 2);
    G3_LDA(0);                // A(t+2)
    G3_LDB(0, 0, 0);          // B0(t+2) -> set0
    BARX();
  }

#pragma unroll
  for (int i = 0; i < 4; i++) {
    const int rbase = m0 + wm * 64 + i * 16 + quad * 4;
#pragma unroll
    for (int jt = 0; jt < 3; jt++)
#pragma unroll
      for (int j = 0; j < 2; j++) {
        const int col = n0 + jt * 128 + wn * 32 + j * 16 + l16;
        const float bv = bias[col];
#pragma unroll
        for (int r = 0; r < 4; r++) {
          const int row = rbase + r;
          const float v = acc[i][jt * 2 + j][r] + bv;
          if (MODE == 0) {
            ((float*)Cv)[(long)row * N + col] = v;
          } else {
            const int b = row >> 11, s = row & (SEQ - 1);
            const int h = (col >> 7) & 15, hd = col & (HDIM - 1);
            const long off = (long)(col >> 11) * NEL +
                ((long)(b * NH + h) * SEQ + s) * HDIM + hd;
            ((ushort*)Cv)[off] = f2bf(v);
          }
        }
      }
  }
}

// ---------------------------------------------------------------------------
// gemm128: 128x256-tile 2-phase bt-GEMM — for N=2048 shapes (out-projection:
// grid 256 = 1 exact round; non-fused fallback path).
// ---------------------------------------------------------------------------
#define STG_A(d, kt) do {                                           \
    const ushort* _s = gA + (long)(kt) * 64;                        \
    ushort* _d = smem + (d) * 8192 + w * 512;                       \
    GLDS(_s, _d);                                                   \
    GLDS(_s + 64 * (long)K, _d + 4096);                             \
  } while (0)

#define STG_B0(d, kt) do {                                          \
    const ushort* _s = gB + (long)(kt) * 64;                        \
    ushort* _d = smem + 16384 + (d) * 16384 + w * 512;              \
    GLDS(_s, _d);                                                   \
    GLDS(_s + 64 * (long)K, _d + 4096);                             \
  } while (0)

#define STG_B1(d, kt) do {                                          \
    const ushort* _s = gB + 128 * (long)K + (long)(kt) * 64;        \
    ushort* _d = smem + 16384 + (d) * 16384 + 8192 + w * 512;       \
    GLDS(_s, _d);                                                   \
    GLDS(_s + 64 * (long)K, _d + 4096);                             \
  } while (0)

#define LDAF(d) do {                                                \
    const ushort* _p = smem + (d) * 8192 + (wm * 64 + l16) * 64;    \
    _Pragma("unroll")                                               \
    for (int _i = 0; _i < 4; _i++) {                                \
      afr[_i][0] = *(const bf16x8*)(_p + _i * 1024 + sw0);          \
      afr[_i][1] = *(const bf16x8*)(_p + _i * 1024 + sw1);          \
    }                                                               \
  } while (0)

#define LDBF(d, nh) do {                                            \
    const ushort* _p = smem + 16384 + (d) * 16384 +                 \
                       ((nh) * 128 + wn * 32 + l16) * 64;           \
    _Pragma("unroll")                                               \
    for (int _j = 0; _j < 2; _j++) {                                \
      bfr[nh][_j][0] = *(const bf16x8*)(_p + _j * 1024 + sw0);      \
      bfr[nh][_j][1] = *(const bf16x8*)(_p + _j * 1024 + sw1);      \
    }                                                               \
  } while (0)

#define MMAP(nh) do {                                               \
    __builtin_amdgcn_s_setprio(1);                                  \
    _Pragma("unroll")                                               \
    for (int _i = 0; _i < 4; _i++)                                  \
      _Pragma("unroll")                                             \
      for (int _j = 0; _j < 2; _j++) {                              \
        acc[_i][(nh) * 2 + _j] = __builtin_amdgcn_mfma_f32_16x16x32_bf16( \
            afr[_i][0], bfr[nh][_j][0], acc[_i][(nh) * 2 + _j], 0, 0, 0); \
        acc[_i][(nh) * 2 + _j] = __builtin_amdgcn_mfma_f32_16x16x32_bf16( \
            afr[_i][1], bfr[nh][_j][1], acc[_i][(nh) * 2 + _j], 0, 0, 0); \
      }                                                             \
    __builtin_amdgcn_s_setprio(0);                                  \
  } while (0)

template <int MODE>
__global__ __launch_bounds__(512, 2) void gemm128(
    const ushort* __restrict__ A, const ushort* __restrict__ Bw,
    const float* __restrict__ bias, void* __restrict__ Cv,
    int M, int N, int K) {
  __shared__ __align__(16) ushort smem[49152];
  const int tid = threadIdx.x;
  const int w = tid >> 6, lane = tid & 63;
  const int quad = lane >> 4, l16 = lane & 15;
  const int wm = w >> 2, wn = w & 3;
  const int nbm = M >> 7, nbn = N >> 8;
  const int rm = nbm >> 1, rn = nbn >> 2;
  const int xcd = blockIdx.x & 7, loc = blockIdx.x >> 3;
  const int bm = (xcd >> 2) * rm + (loc % rm);
  const int bn = (xcd & 3) * rn + (loc / rm);
  const int m0 = bm << 7, n0 = bn << 8;
  const int KT = K >> 6;

  const int srow = tid >> 3;
  const int scol = (((tid & 7) ^ ((tid >> 3) & 7)) << 3);
  const ushort* gA = A + (long)(m0 + srow) * K + scol;
  const ushort* gB = Bw + (long)(n0 + srow) * K + scol;
  const int sw0 = ((quad ^ (l16 & 7)) << 3);
  const int sw1 = (((4 + quad) ^ (l16 & 7)) << 3);

  f32x4 acc[4][4] = {};
  bf16x8 afr[4][2];
  bf16x8 bfr[2][2][2];

  STG_B1(0, 0);
  STG_A(0, 0); STG_B0(0, 0);
  STG_A(1, 1); STG_B0(1, 1);
  WAITV(4);
  BARX();
  LDAF(0); LDBF(0, 0);
  WAITL();
  BARX();

  for (int t = 0; t < KT; t++) {
    const int d = t & 1, nd = d ^ 1;
    const int c1 = (t + 1 < KT) ? t + 1 : 0;
    const int c2 = (t + 2 < KT) ? t + 2 : (t + 2 - KT);
    STG_B1(nd, c1);
    STG_A(d, c2);
    WAITV(8);
    BARX();
    WAITL();
    MMAP(0);
    LDBF(d, 1);
    BARX();
    STG_B0(d, c2);
    WAITV(6);
    BARX();
    WAITL();
    MMAP(1);
    LDAF(nd); LDBF(nd, 0);
    BARX();
  }

#pragma unroll
  for (int i = 0; i < 4; i++) {
    const int rbase = m0 + wm * 64 + i * 16 + quad * 4;
#pragma unroll
    for (int nh = 0; nh < 2; nh++)
#pragma unroll
      for (int j = 0; j < 2; j++) {
        const int col = n0 + nh * 128 + wn * 32 + j * 16 + l16;
        const float bv = bias[col];
#pragma unroll
        for (int r = 0; r < 4; r++) {
          const int row = rbase + r;
          const float v = acc[i][nh * 2 + j][r] + bv;
          if (MODE == 0) {
            ((float*)Cv)[(long)row * N + col] = v;
          } else {
            const int b = row >> 11, s = row & (SEQ - 1);
            const int h = (col >> 7) & 15, hd = col & (HDIM - 1);
            const long off = (long)(col >> 11) * NEL +
                ((long)(b * NH + h) * SEQ + s) * HDIM + hd;
            ((ushort*)Cv)[off] = f2bf(v);
          }
        }
      }
  }
}

// ---------------------------------------------------------------------------
// RoPE in-place on bf16 Q,K in [B,H,S,HD]; reference swaps sin/cos.
// Q pre-scaled by log2(e)/sqrt(HD) so attn uses bare exp2 for softmax.
// ---------------------------------------------------------------------------
__global__ __launch_bounds__(256) void rope_qk(ushort* Q, ushort* Kt) {
  const int gid = blockIdx.x * 256 + threadIdx.x;
  const int n = gid & 4194303;
  const bool isK = (gid >= 4194304);
  ushort* ptr = isK ? Kt : Q;
  const float qs = isK ? 1.0f : 0.12751743f;  // log2(e)/sqrt(128)
  const int p = n & 63;
  const int s = (n >> 6) & (SEQ - 1);
  const int bh = n >> 17;
  const long idx = (long)bh * (SEQ * HDIM) + (long)s * HDIM + p;
  const float invf_rev =
      fast_exp2(-(float)p * 0.2076205059304601f) * 0.15915494309189535f;
  float rev = (float)s * invf_rev;
  rev -= floorf(rev);
  const float sn = __builtin_amdgcn_sinf(rev);
  const float cs = __builtin_amdgcn_cosf(rev);
  const float x1 = bf2f(ptr[idx]);
  const float x2 = bf2f(ptr[idx + 64]);
  ptr[idx]      = f2bf((x1 * sn - x2 * cs) * qs);
  ptr[idx + 64] = f2bf((x2 * sn + x1 * cs) * qs);
}

// ---------------------------------------------------------------------------
// V transpose per head: [B,H,S,HD] -> [B,H,HD,S], 64x64 LDS tiles.
// ---------------------------------------------------------------------------
__global__ __launch_bounds__(256) void transpose_v(const ushort* __restrict__ V,
                                                   ushort* __restrict__ VT) {
  __shared__ ushort lT[64 * 65];
  const int bh = blockIdx.x >> 6;
  const int rem = blockIdx.x & 63;
  const int t0 = (rem >> 1) << 6, d0 = (rem & 1) << 6;
  const ushort* vb = V + (long)bh * (SEQ * HDIM);
  ushort* ob = VT + (long)bh * (SEQ * HDIM);
  const int tid = threadIdx.x;
#pragma unroll
  for (int it = 0; it < 16; it++) {
    const int idx = it * 256 + tid;
    const int r = idx >> 6, c = idx & 63;
    lT[c * 65 + r] = vb[(long)(t0 + r) * HDIM + d0 + c];
  }
  __syncthreads();
#pragma unroll
  for (int it = 0; it < 16; it++) {
    const int idx = it * 256 + tid;
    const int r = idx >> 6, c = idx & 63;
    ob[(long)(d0 + r) * SEQ + t0 + c] = lT[r * 65 + c];
  }
}

// ---------------------------------------------------------------------------
// Flash attention v3 — staging-free. R6 restructure:
// R5 counters: MfmaUtil 26%, HBM 4.4%, 2 blocks/CU (80KB LDS cap) — the K/V
// LDS staging + its barriers were the serialization. Both QK's A-fragment
// (K[t][hd], hd-contiguous) and PV's B-fragment (VT[d][t], t-contiguous) are
// directly b128-loadable from global (same pattern as the Q fragment loads),
// and K/V are L2-resident (catalog: don't stage what caches fit).
// Work split (fragments UNIQUE per wave -> no traffic growth): wave w
// computes the t-quarter [16t x 64q] of S^T (QK; K loads unique) and the
// d-quarter [64q x 32d] of O (PV; VT loads unique). No merge epilogue.
// LDS = P double-buffer only (2x[64][72] = 18.4 KB, odd-granule stride =
// conflict-free); ONE __syncthreads per iteration (P write -> barrier ->
// P read; dbuf covers the cross-iter overwrite hazard). V fragments issue at
// iter start (land before the barrier drain); K(i+1) issues during PV(i).
// launch_bounds(256,3): ~165 VGPR -> 3 blocks/CU = 12 waves/CU.
// ---------------------------------------------------------------------------
__global__ __launch_bounds__(256, 3) void attn(const ushort* __restrict__ Q,
                                               const ushort* __restrict__ Kp,
                                               const ushort* __restrict__ VT,
                                               ushort* __restrict__ ctx) {
  __shared__ __align__(16) ushort lP[2][64 * 72];  // 18432 B
  const int tid = threadIdx.x;
  const int w = tid >> 6, lane = tid & 63;
  const int quad = lane >> 4, l16 = lane & 15;
  // XCD-aware swizzle: 128 consecutive local ids (4 heads) per XCD.
  const int xcd = blockIdx.x & 7, loc = blockIdx.x >> 3;
  const int bh = xcd * 4 + (loc >> 5), qt = loc & 31;
  const long hb = (long)bh * (SEQ * HDIM);
  const int b = bh >> 4, h = bh & 15;

  // Q fragments: all 64 q of the block per wave (B-operand: n=q, k=hd)
  bf16x8 qa[4][4];
#pragma unroll
  for (int qq = 0; qq < 4; qq++)
#pragma unroll
    for (int kc = 0; kc < 4; kc++)
      qa[qq][kc] = *(const bf16x8*)(
          Q + hb + (long)(qt * 64 + qq * 16 + l16) * HDIM + kc * 32 +
          (quad << 3));

  f32x4 o[4][2] = {};    // [qq][nt], d = w*32 + nt*16 + l16
  f32x4 lacc[4] = {};    // row-sum accumulator (ones-MFMA)
  bf16x8 ones;
#pragma unroll
  for (int i = 0; i < 8; i++) ones[i] = (__bf16)1.0f;

  // per-wave fragment bases: K rows t = t0 + w*16 + l16; VT rows
  // d = w*32 + nt*16 + l16.
  const ushort* kW = Kp + hb + (long)(w * 16 + l16) * HDIM + (quad << 3);
  const ushort* vW = VT + hb + (long)(w * 32 + l16) * SEQ + (quad << 3);

  for (int t0 = 0; t0 < SEQ; t0 += 64) {
    ushort* Pb = lP[(t0 >> 6) & 1];

    // V fragments for this iter — issue first, consumed after the barrier
    // (QK + softmax ≈ hundreds of cycles of cover before the barrier drain).
    bf16x8 vf[2][2];  // [nt][kc]
#pragma unroll
    for (int nt = 0; nt < 2; nt++)
#pragma unroll
      for (int kc = 0; kc < 2; kc++)
        vf[nt][kc] = *(const bf16x8*)(vW + (long)nt * (16 * SEQ) + t0 + kc * 32);

    // QK: S^T[16t (this wave's quarter)][64q]. A=K frag (m=t, k=hd).
    f32x4 st[4] = {};  // [qq]
#pragma unroll
    for (int kc = 0; kc < 4; kc++) {
      const bf16x8 kf = *(const bf16x8*)(kW + (long)t0 * HDIM + kc * 32);
#pragma unroll
      for (int qq = 0; qq < 4; qq++)
        st[qq] = __builtin_amdgcn_mfma_f32_16x16x32_bf16(
            kf, qa[qq][kc], st[qq], 0, 0, 0);
    }

    // p = 2^s (Q carries log2e). Lane's q = qq*16+l16 (col),
    // t = w*16 + quad*4 + r -> one b64 store per qq into P[q][t].
    ushort* pW = Pb + l16 * 72 + w * 16 + (quad << 2);
#pragma unroll
    for (int qq = 0; qq < 4; qq++) {
      ushort4 pk;
      pk.x = f2bf_rhu(fast_exp2(st[qq][0]));
      pk.y = f2bf_rhu(fast_exp2(st[qq][1]));
      pk.z = f2bf_rhu(fast_exp2(st[qq][2]));
      pk.w = f2bf_rhu(fast_exp2(st[qq][3]));
      *(ushort4*)(pW + qq * (16 * 72)) = pk;
    }
    __syncthreads();  // P visible to all waves; drains vf loads too

    // PV: A=P[q][t] (m=q, k=t), B=vf (n=d, k=t); 64 t = 2 k-chunks.
#pragma unroll
    for (int qq = 0; qq < 4; qq++) {
      const ushort* pR = Pb + (qq * 16 + l16) * 72 + (quad << 3);
      const bf16x8 pa0 = *(const bf16x8*)(pR);
      const bf16x8 pa1 = *(const bf16x8*)(pR + 32);
      lacc[qq] = __builtin_amdgcn_mfma_f32_16x16x32_bf16(
          pa0, ones, lacc[qq], 0, 0, 0);
      lacc[qq] = __builtin_amdgcn_mfma_f32_16x16x32_bf16(
          pa1, ones, lacc[qq], 0, 0, 0);
#pragma unroll
      for (int nt = 0; nt < 2; nt++) {
        o[qq][nt] = __builtin_amdgcn_mfma_f32_16x16x32_bf16(
            pa0, vf[nt][0], o[qq][nt], 0, 0, 0);
        o[qq][nt] = __builtin_amdgcn_mfma_f32_16x16x32_bf16(
            pa1, vf[nt][1], o[qq][nt], 0, 0, 0);
      }
    }
  }

  // Store: each wave owns [64 q] x [its 32-d quarter] — no merge.
#pragma unroll
  for (int qq = 0; qq < 4; qq++)
#pragma unroll
    for (int r = 0; r < 4; r++) {
      const float inv = 1.0f / lacc[qq][r];
      const int s = qt * 64 + qq * 16 + quad * 4 + r;
      const long base = ((long)(b * SEQ + s)) * DMODEL + h * HDIM + w * 32;
#pragma unroll
      for (int nt = 0; nt < 2; nt++)
        ctx[base + nt * 16 + l16] = f2bf(o[qq][nt][r] * inv);
    }
}

// ---------------------------------------------------------------------------
extern "C" void kernel_launch(void* const* d_in, const int* in_sizes, int n_in,
                              void* d_out, int out_size, void* d_ws, size_t ws_size,
                              hipStream_t stream) {
  const float* hid = (const float*)d_in[0];
  const float* Wq = (const float*)d_in[1];
  const float* bq = (const float*)d_in[2];
  const float* Wk = (const float*)d_in[3];
  const float* bk = (const float*)d_in[4];
  const float* Wv = (const float*)d_in[5];
  const float* bv = (const float*)d_in[6];
  const float* Wo = (const float*)d_in[7];
  const float* bo = (const float*)d_in[8];
  float* out = (float*)d_out;
  ushort* ws = (ushort*)d_ws;

  ushort* qw   = ws;            // [B,H,S,HD] bf16  (Q/K/V contiguous!)
  ushort* kw   = ws + NEL;
  ushort* vw   = ws + 2 * NEL;  // reused as ctx after transpose_v
  ushort* hidB = ws + 3 * NEL;  // hidden bf16; reused as VT after QKV GEMM(s)
  ushort* wB   = ws + 4 * NEL;  // weight bf16: 1x or 3x [D,D]

  dim3 blk(256);
  dim3 blkG(512);
  conv_f32_bf16<<<(int)(NEL / 4 / 256), blk, 0, stream>>>(hid, hidB, NEL / 4);

  if (ws_size >= FUSED_WS) {
    // fused QKV: one N=6144 GEMM, (4096/128)*(6144/384) = 512 = 2 exact rounds
    conv_f32_bf16<<<(int)(WEL / 4 / 256), blk, 0, stream>>>(Wq, wB, WEL / 4);
    conv_f32_bf16<<<(int)(WEL / 4 / 256), blk, 0, stream>>>(Wk, wB + WEL, WEL / 4);
    conv_f32_bf16<<<(int)(WEL / 4 / 256), blk, 0, stream>>>(Wv, wB + 2 * WEL, WEL / 4);
    float* bc = (float*)(wB + 3 * WEL);
    bias_cat<<<24, blk, 0, stream>>>(bq, bk, bv, bc);
    gemm384<1><<<512, blkG, 0, stream>>>(hidB, wB, bc, qw, MTOT, 3 * DMODEL, DMODEL);
  } else {
    conv_f32_bf16<<<(int)(WEL / 4 / 256), blk, 0, stream>>>(Wq, wB, WEL / 4);
    gemm128<1><<<256, blkG, 0, stream>>>(hidB, wB, bq, qw, MTOT, DMODEL, DMODEL);
    conv_f32_bf16<<<(int)(WEL / 4 / 256), blk, 0, stream>>>(Wk, wB, WEL / 4);
    gemm128<1><<<256, blkG, 0, stream>>>(hidB, wB, bk, kw, MTOT, DMODEL, DMODEL);
    conv_f32_bf16<<<(int)(WEL / 4 / 256), blk, 0, stream>>>(Wv, wB, WEL / 4);
    gemm128<1><<<256, blkG, 0, stream>>>(hidB, wB, bv, vw, MTOT, DMODEL, DMODEL);
  }

  rope_qk<<<32768, blk, 0, stream>>>(qw, kw);

  // V^T into the hidB slot (hidden no longer needed as GEMM input)
  ushort* vtw = hidB;
  transpose_v<<<2048, blk, 0, stream>>>(vw, vtw);

  // attn writes ctx into the vw slot (V superseded by VT)
  ushort* cw = vw;
  attn<<<1024, blk, 0, stream>>>(qw, kw, vtw, cw);

  // out-projection: 32*8 = 256 blocks = exactly 1 round
  conv_f32_bf16<<<(int)(WEL / 4 / 256), blk, 0, stream>>>(Wo, wB, WEL / 4);
  gemm128<0><<<256, blkG, 0, stream>>>(cw, wB, bo, out, MTOT, DMODEL, DMODEL);
}